// Round 8
// baseline (605.901 us; speedup 1.0000x reference)
//
#include <hip/hip_runtime.h>

#define B_ 8
#define L_ 512
#define K_ 30
#define NIN_ 384
#define HES 11520          // floats per site in h_E
#define BUFW 136           // buf1 row stride (ushort)
#define GFW 96             // geoF row stride (ushort)
#define PWU 4608           // ushorts per wave arena (9216 B)
// f32 indices inside wave arena:
#define R0_OFF 0
#define T0_OFF 9
#define PL0_OFF 12
#define NPG_OFF 40
#define PLF_OFF 760
#define NM_OFF 640
#define GEOF_OFF 1520      // ushort index (byte 3040), overlays dead PlFull

// ws fragment-ordered weights (ushort, bf16):
#define W1F_OFF 0
#define W2F_OFF 77824
#define W3F_OFF 94208
#define WIF_OFF 110592
#define WOF_OFF 176128
#define WPF_OFF 241664
// bf16 activation copies:
#define HE16_OFF 245760ULL                  // 47185920 ushorts
#define HV16_OFF (245760ULL + 47185920ULL)  // 524288 ushorts
#define NEED_BYTES ((HV16_OFF + 524288ULL) * 2ULL)   // 95,911,936 B

typedef __attribute__((ext_vector_type(8))) short short8;
typedef __attribute__((ext_vector_type(8))) unsigned short ushort8;
typedef __attribute__((ext_vector_type(4))) float floatx4;
typedef __attribute__((ext_vector_type(4))) float f32x4;

__device__ __forceinline__ float b2f(unsigned short u) {
    union { unsigned int i; float f; } x; x.i = ((unsigned int)u) << 16; return x.f;
}
__device__ __forceinline__ unsigned short f2b(float f) {
    unsigned int u = __builtin_bit_cast(unsigned int, f);
    return (unsigned short)((u + 0x7fffu + ((u >> 16) & 1u)) >> 16);
}
__device__ __forceinline__ float gelu_f(float x) {
    return 0.5f * x * (1.0f + erff(x * 0.70710678118654752440f));
}
__device__ __forceinline__ short8 pack8(const float* p) {
    f32x4 lo = *(const f32x4*)p;
    f32x4 hi = *(const f32x4*)(p + 4);
    short8 r;
    r[0] = (short)f2b(lo[0]); r[1] = (short)f2b(lo[1]);
    r[2] = (short)f2b(lo[2]); r[3] = (short)f2b(lo[3]);
    r[4] = (short)f2b(hi[0]); r[5] = (short)f2b(hi[1]);
    r[6] = (short)f2b(hi[2]); r[7] = (short)f2b(hi[3]);
    return r;
}
__device__ __forceinline__ float dot8(const float* hp, ushort8 v) {
    return hp[0] * b2f(v[0]) + hp[1] * b2f(v[1]) + hp[2] * b2f(v[2]) + hp[3] * b2f(v[3]) +
           hp[4] * b2f(v[4]) + hp[5] * b2f(v[5]) + hp[6] * b2f(v[6]) + hp[7] * b2f(v[7]);
}

// fragment-order weight transposes (unchanged from R7)
__global__ __launch_bounds__(256) void prep_kernel(
        const float* __restrict__ W1, const float* __restrict__ W2,
        const float* __restrict__ W3, const float* __restrict__ Wi,
        const float* __restrict__ Wo, const float* __restrict__ Wp,
        unsigned short* __restrict__ ws) {
    int idx = blockIdx.x * 256 + threadIdx.x;
    if (idx < 94208 || (idx >= 241664 && idx < 245760)) {
        const float* in; int i, KC, Kreal, Nreal, Nld;
        if (idx < 77824)      { in = W1; i = idx;          KC = 19; Kreal = 584; Nreal = 128; Nld = 128; }
        else if (idx < 94208) { in = W2; i = idx - 77824;  KC = 4;  Kreal = 128; Nreal = 128; Nld = 128; }
        else                  { in = Wp; i = idx - 241664; KC = 4;  Kreal = 128; Nreal = 24;  Nld = 24;  }
        int f = i >> 9, r = i & 511;
        int ct = f / KC, kc = f % KC;
        int lane = r >> 3, j = r & 7;
        int q = lane >> 4, l = lane & 15;
        int k = kc * 32 + q * 8 + j, n = ct * 16 + l;
        ws[idx] = (k < Kreal && n < Nreal) ? f2b(in[k * Nld + n]) : (unsigned short)0;
    } else if (idx < 110592) {
        int i = idx - 94208;
        int f = i >> 9, r = i & 511;
        int ct = f >> 2, kc = f & 3;
        int lane = r >> 3, j = r & 7;
        int q = lane >> 4, l = lane & 15;
        ws[idx] = f2b(W3[(kc * 32 + q * 8 + j) * 128 + ct * 16 + l]);
    } else if (idx < 176128) {
        int i = idx - 110592;
        int c8 = i >> 12, r = i & 4095;
        int o = r >> 3, ii = r & 7;
        ws[idx] = f2b(Wi[(c8 * 8 + ii) * 512 + o]);
    } else if (idx < 241664) {
        int i = idx - 176128;
        int o8 = i >> 10, r = i & 1023;
        int c = r >> 3, ii = r & 7;
        ws[idx] = f2b(Wo[(o8 * 8 + ii) * 128 + c]);
    }
}

// streaming f32 -> bf16 cast of h_E and h_V into ws
__global__ __launch_bounds__(256) void cast_kernel(
        const float* __restrict__ h_E, const float* __restrict__ h_V,
        unsigned short* __restrict__ ws) {
    const long long NHE8 = 47185920LL / 8;   // 5,898,240
    const long long NTOT = NHE8 + 524288LL / 8;
    long long stride = (long long)gridDim.x * 256;
    for (long long i = (long long)blockIdx.x * 256 + threadIdx.x; i < NTOT; i += stride) {
        const float* src; unsigned short* dst;
        if (i < NHE8) { src = h_E + i * 8;            dst = ws + HE16_OFF + i * 8; }
        else          { long long j = i - NHE8; src = h_V + j * 8; dst = ws + HV16_OFF + j * 8; }
        f32x4 lo = *(const f32x4*)src;
        f32x4 hi = *(const f32x4*)(src + 4);
        ushort8 o;
        o[0] = f2b(lo[0]); o[1] = f2b(lo[1]); o[2] = f2b(lo[2]); o[3] = f2b(lo[3]);
        o[4] = f2b(hi[0]); o[5] = f2b(hi[1]); o[6] = f2b(hi[2]); o[7] = f2b(hi[3]);
        *(ushort8*)dst = o;
    }
}

// One wave per site (64-thread blocks), zero __syncthreads.
template <int USEB>
__global__ __launch_bounds__(64, 3) void main_kernel(
    const float* __restrict__ h_V,
    const float* __restrict__ h_E,
    const float* __restrict__ Xn,
    const float* __restrict__ mask_V,
    const float* __restrict__ mask_attend,
    const float* __restrict__ bp,
    const float* __restrict__ b1g,
    const float* __restrict__ b2g,
    const float* __restrict__ b3g,
    const float* __restrict__ big,
    const float* __restrict__ bog,
    const float* __restrict__ g1,
    const float* __restrict__ be1,
    const float* __restrict__ g2,
    const float* __restrict__ be2,
    const unsigned short* __restrict__ wsT,
    float* __restrict__ out) {

    __shared__ __align__(16) unsigned short wl[PWU];

    const int lane = threadIdx.x;
    const int quad = lane >> 4;
    const int l16  = lane & 15;
    const int ko   = quad * 8;
    const int site = blockIdx.x;

    unsigned short* buf1 = wl;
    unsigned short* geoF = wl + GEOF_OFF;
    float*          Fv   = (float*)wl;

    const unsigned short* W1F = wsT + W1F_OFF;
    const unsigned short* W2F = wsT + W2F_OFF;
    const unsigned short* W3F = wsT + W3F_OFF;
    const unsigned short* WiF = wsT + WIF_OFF;
    const unsigned short* WoF = wsT + WOF_OFF;
    const unsigned short* WpF = wsT + WPF_OFF;

    const float* hEb = h_E + (size_t)site * HES;
    const float* hVb = h_V + site * 128;
    const unsigned short* hE16 = wsT + HE16_OFF + (size_t)site * HES;
    const unsigned short* hV16 = wsT + HV16_OFF + (size_t)site * 128;
    const short8 z8 = {0, 0, 0, 0, 0, 0, 0, 0};

    float maskR[2][4];
    for (int rt = 0; rt < 2; ++rt)
        for (int r = 0; r < 4; ++r) {
            int row = rt * 16 + quad * 4 + r;
            maskR[rt][r] = (row < K_) ? mask_attend[site * K_ + row] * (1.0f / 30.0f) : 0.0f;
        }

    // ---- frames in registers (lanes 0..29): R[i][j]=e_j[i] ----
    float Rr[9], Tt[3];
    if (lane < K_) {
        const float* xp = Xn + ((size_t)site * K_ + lane) * 9;
        float Nx = xp[0], Ny = xp[1], Nz = xp[2];
        float Ax = xp[3], Ay = xp[4], Az = xp[5];
        float Cx = xp[6], Cy = xp[7], Cz = xp[8];
        float e0x = Ax - Nx, e0y = Ay - Ny, e0z = Az - Nz;
        float r0 = 1.0f / sqrtf(e0x * e0x + e0y * e0y + e0z * e0z + 1e-8f);
        e0x *= r0; e0y *= r0; e0z *= r0;
        float u1x = Cx - Ax, u1y = Cy - Ay, u1z = Cz - Az;
        float d = e0x * u1x + e0y * u1y + e0z * u1z;
        u1x -= e0x * d; u1y -= e0y * d; u1z -= e0z * d;
        float r1 = 1.0f / sqrtf(u1x * u1x + u1y * u1y + u1z * u1z + 1e-8f);
        u1x *= r1; u1y *= r1; u1z *= r1;
        Rr[0] = e0x; Rr[1] = u1x; Rr[2] = e0y * u1z - e0z * u1y;
        Rr[3] = e0y; Rr[4] = u1y; Rr[5] = e0z * u1x - e0x * u1z;
        Rr[6] = e0z; Rr[7] = u1z; Rr[8] = e0x * u1y - e0y * u1x;
        Tt[0] = Ax; Tt[1] = Ay; Tt[2] = Az;
    }

    // ---- p_ln MFMA -> PlFull LDS ----
    {
        floatx4 a[2][2] = {{{0,0,0,0},{0,0,0,0}},{{0,0,0,0},{0,0,0,0}}};
        for (int kc = 0; kc < 4; ++kc) {
            int col = 256 + kc * 32 + ko;
            short8 fa0, fa1;
            int r1 = 16 + l16;
            if (USEB) {
                fa0 = *(const short8*)(hE16 + l16 * NIN_ + col);
                fa1 = (r1 < K_) ? *(const short8*)(hE16 + r1 * NIN_ + col) : z8;
            } else {
                fa0 = pack8(hEb + l16 * NIN_ + col);
                fa1 = (r1 < K_) ? pack8(hEb + r1 * NIN_ + col) : z8;
            }
            for (int ct = 0; ct < 2; ++ct) {
                short8 fb = *(const short8*)(WpF + (ct * 4 + kc) * 512 + lane * 8);
                a[0][ct] = __builtin_amdgcn_mfma_f32_16x16x32_bf16(fa0, fb, a[0][ct], 0, 0, 0);
                a[1][ct] = __builtin_amdgcn_mfma_f32_16x16x32_bf16(fa1, fb, a[1][ct], 0, 0, 0);
            }
        }
        for (int ct = 0; ct < 2; ++ct) {
            int ccol = ct * 16 + l16;
            if (ccol < 24) {
                float bpc = bp[ccol];
                for (int rt = 0; rt < 2; ++rt)
                    for (int i = 0; i < 4; ++i) {
                        int row = rt * 16 + quad * 4 + i;
                        if (row < K_) Fv[PLF_OFF + row * 24 + ccol] = a[rt][ct][i] + bpc;
                    }
            }
        }
    }

    // ---- npg by lane k ----
    if (lane < K_) {
        float pl[24];
        #pragma unroll
        for (int c = 0; c < 24; ++c) pl[c] = Fv[PLF_OFF + lane * 24 + c];
        if (lane == 0) {
            #pragma unroll
            for (int i = 0; i < 9; ++i) Fv[R0_OFF + i] = Rr[i];
            Fv[T0_OFF] = Tt[0]; Fv[T0_OFF + 1] = Tt[1]; Fv[T0_OFF + 2] = Tt[2];
            #pragma unroll
            for (int c = 0; c < 24; ++c) Fv[PL0_OFF + c] = pl[c];
        }
        #pragma unroll
        for (int n = 0; n < 8; ++n) {
            float p0 = pl[n * 3], p1 = pl[n * 3 + 1], p2 = pl[n * 3 + 2];
            #pragma unroll
            for (int i = 0; i < 3; ++i)
                Fv[NPG_OFF + lane * 24 + n * 3 + i] =
                    Rr[i * 3 + 0] * p0 + Rr[i * 3 + 1] * p1 + Rr[i * 3 + 2] * p2 + Tt[i];
        }
    }

    // ---- features -> geoF (overlays dead PlFull) ----
    for (int id = lane; id < 720; id += 64) geoF[(id / 24) * GFW + 72 + id % 24] = 0;
    {
        float R00 = Fv[0], R01 = Fv[1], R02 = Fv[2], R03 = Fv[3], R04 = Fv[4];
        float R05 = Fv[5], R06 = Fv[6], R07 = Fv[7], R08 = Fv[8];
        float T00 = Fv[9], T01 = Fv[10], T02 = Fv[11];
        for (int id = lane; id < 240; id += 64) {
            int k = id >> 3, n = id & 7;
            float p0 = Fv[PL0_OFF + n * 3], p1 = Fv[PL0_OFF + n * 3 + 1], p2 = Fv[PL0_OFF + n * 3 + 2];
            float q0g = Fv[NPG_OFF + n * 3], q1g = Fv[NPG_OFF + n * 3 + 1], q2g = Fv[NPG_OFF + n * 3 + 2];
            float a0 = Fv[NPG_OFF + k * 24 + n * 3];
            float a1 = Fv[NPG_OFF + k * 24 + n * 3 + 1];
            float a2 = Fv[NPG_OFF + k * 24 + n * 3 + 2];
            float d0 = a0 - T00, d1 = a1 - T01, d2 = a2 - T02;
            float nl0 = R00 * d0 + R03 * d1 + R06 * d2;
            float nl1 = R01 * d0 + R04 * d1 + R07 * d2;
            float nl2 = R02 * d0 + R05 * d1 + R08 * d2;
            unsigned short* gf = geoF + k * GFW;
            gf[0 + n * 3] = f2b(p0); gf[1 + n * 3] = f2b(p1); gf[2 + n * 3] = f2b(p2);
            gf[24 + n] = f2b(sqrtf(p0 * p0 + p1 * p1 + p2 * p2 + 1e-8f));
            gf[32 + n * 3] = f2b(nl0); gf[33 + n * 3] = f2b(nl1); gf[34 + n * 3] = f2b(nl2);
            gf[56 + n] = f2b(sqrtf(nl0 * nl0 + nl1 * nl1 + nl2 * nl2 + 1e-8f));
            float q0 = q0g - a0, q1 = q1g - a1, q2 = q2g - a2;
            gf[64 + n] = f2b(sqrtf(q0 * q0 + q1 * q1 + q2 * q2 + 1e-8f));
        }
    }

    // ---- stage 1: [32 x 608] @ W1 -> gelu -> buf1 ----
    {
        floatx4 acc[2][8];
        for (int rt = 0; rt < 2; ++rt) for (int ct = 0; ct < 8; ++ct) acc[rt][ct] = (floatx4){0,0,0,0};
        for (int kc = 0; kc < 4; ++kc) {            // h_V rows (identical)
            int col = kc * 32 + ko;
            short8 fa = USEB ? *(const short8*)(hV16 + col) : pack8(hVb + col);
            for (int ct = 0; ct < 8; ++ct) {
                short8 fb = *(const short8*)(W1F + (ct * 19 + kc) * 512 + lane * 8);
                acc[0][ct] = __builtin_amdgcn_mfma_f32_16x16x32_bf16(fa, fb, acc[0][ct], 0, 0, 0);
                acc[1][ct] = __builtin_amdgcn_mfma_f32_16x16x32_bf16(fa, fb, acc[1][ct], 0, 0, 0);
            }
        }
        for (int kc = 0; kc < 12; ++kc) {           // h_E
            int col = kc * 32 + ko;
            short8 fa0, fa1;
            int r1 = 16 + l16;
            if (USEB) {
                fa0 = *(const short8*)(hE16 + l16 * NIN_ + col);
                fa1 = (r1 < K_) ? *(const short8*)(hE16 + r1 * NIN_ + col) : z8;
            } else {
                fa0 = pack8(hEb + l16 * NIN_ + col);
                fa1 = (r1 < K_) ? pack8(hEb + r1 * NIN_ + col) : z8;
            }
            for (int ct = 0; ct < 8; ++ct) {
                short8 fb = *(const short8*)(W1F + (ct * 19 + 4 + kc) * 512 + lane * 8);
                acc[0][ct] = __builtin_amdgcn_mfma_f32_16x16x32_bf16(fa0, fb, acc[0][ct], 0, 0, 0);
                acc[1][ct] = __builtin_amdgcn_mfma_f32_16x16x32_bf16(fa1, fb, acc[1][ct], 0, 0, 0);
            }
        }
        for (int kc = 0; kc < 3; ++kc) {            // geoF (LDS)
            int col = kc * 32 + ko;
            short8 fa0 = *(const short8*)&geoF[l16 * GFW + col];
            int r1 = 16 + l16;
            short8 fa1 = (r1 < K_) ? *(const short8*)&geoF[r1 * GFW + col] : z8;
            for (int ct = 0; ct < 8; ++ct) {
                short8 fb = *(const short8*)(W1F + (ct * 19 + 16 + kc) * 512 + lane * 8);
                acc[0][ct] = __builtin_amdgcn_mfma_f32_16x16x32_bf16(fa0, fb, acc[0][ct], 0, 0, 0);
                acc[1][ct] = __builtin_amdgcn_mfma_f32_16x16x32_bf16(fa1, fb, acc[1][ct], 0, 0, 0);
            }
        }
        for (int ct = 0; ct < 8; ++ct) {
            int col = ct * 16 + l16;
            float bb = b1g[col];
            for (int rt = 0; rt < 2; ++rt)
                for (int r = 0; r < 4; ++r) {
                    int row = rt * 16 + quad * 4 + r;
                    buf1[row * BUFW + col] = f2b(gelu_f(acc[rt][ct][r] + bb));
                }
        }
    }

    // ---- stage 2: buf1 @ W2 -> gelu -> buf1 ----
    {
        short8 Af[2][4];
        for (int kc = 0; kc < 4; ++kc) {
            Af[0][kc] = *(const short8*)&buf1[l16 * BUFW + kc * 32 + ko];
            Af[1][kc] = *(const short8*)&buf1[(16 + l16) * BUFW + kc * 32 + ko];
        }
        floatx4 acc[2][8];
        for (int rt = 0; rt < 2; ++rt) for (int ct = 0; ct < 8; ++ct) acc[rt][ct] = (floatx4){0,0,0,0};
        for (int kc = 0; kc < 4; ++kc)
            for (int ct = 0; ct < 8; ++ct) {
                short8 fb = *(const short8*)(W2F + (ct * 4 + kc) * 512 + lane * 8);
                acc[0][ct] = __builtin_amdgcn_mfma_f32_16x16x32_bf16(Af[0][kc], fb, acc[0][ct], 0, 0, 0);
                acc[1][ct] = __builtin_amdgcn_mfma_f32_16x16x32_bf16(Af[1][kc], fb, acc[1][ct], 0, 0, 0);
            }
        for (int ct = 0; ct < 8; ++ct) {
            int col = ct * 16 + l16;
            float bb = b2g[col];
            for (int rt = 0; rt < 2; ++rt)
                for (int r = 0; r < 4; ++r) {
                    int row = rt * 16 + quad * 4 + r;
                    buf1[row * BUFW + col] = f2b(gelu_f(acc[rt][ct][r] + bb));
                }
        }
    }

    // ---- stage 3: buf1 @ W3 + b3 -> masked mean -> nm ----
    {
        short8 Af[2][4];
        for (int kc = 0; kc < 4; ++kc) {
            Af[0][kc] = *(const short8*)&buf1[l16 * BUFW + kc * 32 + ko];
            Af[1][kc] = *(const short8*)&buf1[(16 + l16) * BUFW + kc * 32 + ko];
        }
        floatx4 acc[2][8];
        for (int rt = 0; rt < 2; ++rt) for (int ct = 0; ct < 8; ++ct) acc[rt][ct] = (floatx4){0,0,0,0};
        for (int kc = 0; kc < 4; ++kc)
            for (int ct = 0; ct < 8; ++ct) {
                short8 fb = *(const short8*)(W3F + (ct * 4 + kc) * 512 + lane * 8);
                acc[0][ct] = __builtin_amdgcn_mfma_f32_16x16x32_bf16(Af[0][kc], fb, acc[0][ct], 0, 0, 0);
                acc[1][ct] = __builtin_amdgcn_mfma_f32_16x16x32_bf16(Af[1][kc], fb, acc[1][ct], 0, 0, 0);
            }
        for (int ct = 0; ct < 8; ++ct) {
            int col = ct * 16 + l16;
            float bb = b3g[col];
            float cs = 0.0f;
            for (int rt = 0; rt < 2; ++rt)
                for (int r = 0; r < 4; ++r)
                    cs += (acc[rt][ct][r] + bb) * maskR[rt][r];
            cs += __shfl_xor(cs, 16, 64);
            cs += __shfl_xor(cs, 32, 64);
            if (lane < 16) Fv[NM_OFF + col] = cs;
        }
    }

    // ---- tail: LN1 -> FFN -> LN2 -> out ----
    {
        int c0 = lane, c1 = lane + 64;
        float xb0 = hVb[c0] + Fv[NM_OFF + c0];
        float xb1 = hVb[c1] + Fv[NM_OFF + c1];
        float s = xb0 + xb1, q = xb0 * xb0 + xb1 * xb1;
        for (int o = 32; o; o >>= 1) { s += __shfl_xor(s, o, 64); q += __shfl_xor(q, o, 64); }
        float m = s * (1.0f / 128.0f);
        float inv = 1.0f / sqrtf(q * (1.0f / 128.0f) - m * m + 1e-5f);
        float h0 = (xb0 - m) * inv * g1[c0] + be1[c0];
        float h1 = (xb1 - m) * inv * g1[c1] + be1[c1];
        Fv[c0] = h0; Fv[c1] = h1;

        for (int j = 0; j < 8; ++j) {
            int o = lane + 64 * j;
            float sa = big[o], sb = 0.0f;
            for (int c8 = 0; c8 < 16; c8 += 2) {
                ushort8 v0 = *(const ushort8*)(WiF + c8 * 4096 + o * 8);
                ushort8 v1 = *(const ushort8*)(WiF + (c8 + 1) * 4096 + o * 8);
                sa += dot8(&Fv[c8 * 8], v0);
                sb += dot8(&Fv[c8 * 8 + 8], v1);
            }
            Fv[128 + o] = gelu_f(sa + sb);
        }

        float d0a = bog[c0], d0b = 0.0f, d1a = bog[c1], d1b = 0.0f;
        for (int o8 = 0; o8 < 64; o8 += 2) {
            ushort8 v0  = *(const ushort8*)(WoF + o8 * 1024 + c0 * 8);
            ushort8 v0n = *(const ushort8*)(WoF + (o8 + 1) * 1024 + c0 * 8);
            ushort8 v1  = *(const ushort8*)(WoF + o8 * 1024 + c1 * 8);
            ushort8 v1n = *(const ushort8*)(WoF + (o8 + 1) * 1024 + c1 * 8);
            const float* gp = &Fv[128 + o8 * 8];
            d0a += dot8(gp, v0);  d0b += dot8(gp + 8, v0n);
            d1a += dot8(gp, v1);  d1b += dot8(gp + 8, v1n);
        }
        float y0 = h0 + d0a + d0b, y1 = h1 + d1a + d1b;
        float s2 = y0 + y1, q2 = y0 * y0 + y1 * y1;
        for (int o = 32; o; o >>= 1) { s2 += __shfl_xor(s2, o, 64); q2 += __shfl_xor(q2, o, 64); }
        float m2 = s2 * (1.0f / 128.0f);
        float inv2 = 1.0f / sqrtf(q2 * (1.0f / 128.0f) - m2 * m2 + 1e-5f);
        float mv = mask_V[site];
        out[site * 128 + c0] = ((y0 - m2) * inv2 * g2[c0] + be2[c0]) * mv;
        out[site * 128 + c1] = ((y1 - m2) * inv2 * g2[c1] + be2[c1]) * mv;
    }
}

extern "C" void kernel_launch(void* const* d_in, const int* in_sizes, int n_in,
                              void* d_out, int out_size, void* d_ws, size_t ws_size,
                              hipStream_t stream) {
    const float* h_V = (const float*)d_in[0];
    const float* h_E = (const float*)d_in[1];
    // d_in[2] = E_idx (int32, unused by reference)
    const float* Xn  = (const float*)d_in[3];
    const float* mV  = (const float*)d_in[4];
    const float* mA  = (const float*)d_in[5];
    const float* Wp  = (const float*)d_in[6];
    const float* bp  = (const float*)d_in[7];
    const float* W1  = (const float*)d_in[8];
    const float* b1  = (const float*)d_in[9];
    const float* W2  = (const float*)d_in[10];
    const float* b2  = (const float*)d_in[11];
    const float* W3  = (const float*)d_in[12];
    const float* b3  = (const float*)d_in[13];
    const float* Wi  = (const float*)d_in[14];
    const float* bi  = (const float*)d_in[15];
    const float* Wo  = (const float*)d_in[16];
    const float* bo  = (const float*)d_in[17];
    const float* g1  = (const float*)d_in[18];
    const float* be1 = (const float*)d_in[19];
    const float* g2  = (const float*)d_in[20];
    const float* be2 = (const float*)d_in[21];
    unsigned short* ws = (unsigned short*)d_ws;
    float* out = (float*)d_out;

    prep_kernel<<<960, 256, 0, stream>>>(W1, W2, W3, Wi, Wo, Wp, ws);
    if (ws_size >= (size_t)NEED_BYTES) {
        cast_kernel<<<2048, 256, 0, stream>>>(h_E, h_V, ws);
        main_kernel<1><<<B_ * L_, 64, 0, stream>>>(h_V, h_E, Xn, mV, mA, bp,
                                                   b1, b2, b3, bi, bo,
                                                   g1, be1, g2, be2, ws, out);
    } else {
        main_kernel<0><<<B_ * L_, 64, 0, stream>>>(h_V, h_E, Xn, mV, mA, bp,
                                                   b1, b2, b3, bi, bo,
                                                   g1, be1, g2, be2, ws, out);
    }
}